// Round 1
// baseline (404.254 us; speedup 1.0000x reference)
//
#include <hip/hip_runtime.h>
#include <hip/hip_bf16.h>

// GraphNeuralAssociator: GCN(3 layers, fp32) + all-pairs edge MLP.
// Edge MLP layer 1 is factorized: h1(i,j) = relu(Amat[i] + Bmat[j]) where
// Amat = emb@w1[:256]+b1, Bmat = emb@w1[256:]. Layer 2 (the only big GEMM,
// ~68.6 GF) runs as bf16 MFMA 16x16x32 with fp32 accum; layer 3 + sigmoid
// fused into the epilogue (h2 never materialized).

#define NN 512
#define FF 256
#define HH 512

typedef __attribute__((ext_vector_type(8))) short s8v;   // 8 x bf16 bits
typedef __attribute__((ext_vector_type(4))) float f4v;   // MFMA acc

__device__ __forceinline__ ushort f2bf(float f) {
  // round-to-nearest-even f32 -> bf16 (finite values)
  unsigned u = __float_as_uint(f);
  unsigned r = (u + 0x7fffu + ((u >> 16) & 1u)) >> 16;
  return (ushort)r;
}

// ---------------- row-normalize adjacency ----------------
__global__ __launch_bounds__(256)
void rownorm_kernel(const float* __restrict__ adj, float* __restrict__ adjn) {
  int row = blockIdx.x;
  int tid = threadIdx.x;
  const float* r = adj + row * NN;
  float a0 = r[tid], a1 = r[tid + 256];
  float s = a0 + a1;
#pragma unroll
  for (int m = 1; m < 64; m <<= 1) s += __shfl_xor(s, m);
  __shared__ float wsum[4];
  if ((tid & 63) == 0) wsum[tid >> 6] = s;
  __syncthreads();
  float inv = 1.f / (wsum[0] + wsum[1] + wsum[2] + wsum[3] + 1e-8f);
  float* o = adjn + row * NN;
  o[tid] = a0 * inv;
  o[tid + 256] = a1 * inv;
}

// ---------------- generic fp32 GEMM (64x64 tile, optional dual-output via z) ----
// C = [relu]( A@B + bias + add )
template <bool RELU>
__global__ __launch_bounds__(256)
void gemm_ts(int M, int N, int K,
             const float* __restrict__ A, int lda,
             const float* __restrict__ B0, const float* __restrict__ B1, int ldb,
             const float* __restrict__ bias0, const float* __restrict__ bias1,
             const float* __restrict__ add0, const float* __restrict__ add1, int ldadd,
             float* __restrict__ C0, float* __restrict__ C1, int ldc)
{
  const float* B = blockIdx.z ? B1 : B0;
  const float* bias = blockIdx.z ? bias1 : bias0;
  const float* add = blockIdx.z ? add1 : add0;
  float* C = blockIdx.z ? C1 : C0;
  const int n0 = blockIdx.x * 64;
  const int m0 = blockIdx.y * 64;
  const int tid = threadIdx.x;
  const int ty = tid >> 4, tx = tid & 15;

  __shared__ float As[16][68];  // As[k][m]
  __shared__ float Bs[16][68];  // Bs[k][n]
  float4 acc[4] = {};

  for (int k0 = 0; k0 < K; k0 += 16) {
#pragma unroll
    for (int p = 0; p < 4; ++p) {
      int e = tid + p * 256;
      As[e & 15][e >> 4] = A[(m0 + (e >> 4)) * lda + k0 + (e & 15)];
    }
#pragma unroll
    for (int p = 0; p < 4; ++p) {
      int e = tid + p * 256;
      Bs[e >> 6][e & 63] = B[(k0 + (e >> 6)) * ldb + n0 + (e & 63)];
    }
    __syncthreads();
#pragma unroll
    for (int k = 0; k < 16; ++k) {
      float4 a = *(const float4*)&As[k][ty * 4];
      float4 b = *(const float4*)&Bs[k][tx * 4];
      acc[0].x += a.x * b.x; acc[0].y += a.x * b.y; acc[0].z += a.x * b.z; acc[0].w += a.x * b.w;
      acc[1].x += a.y * b.x; acc[1].y += a.y * b.y; acc[1].z += a.y * b.z; acc[1].w += a.y * b.w;
      acc[2].x += a.z * b.x; acc[2].y += a.z * b.y; acc[2].z += a.z * b.z; acc[2].w += a.z * b.w;
      acc[3].x += a.w * b.x; acc[3].y += a.w * b.y; acc[3].z += a.w * b.z; acc[3].w += a.w * b.w;
    }
    __syncthreads();
  }

  float4 bv = {0.f, 0.f, 0.f, 0.f};
  if (bias) bv = *(const float4*)&bias[n0 + tx * 4];
#pragma unroll
  for (int r = 0; r < 4; ++r) {
    int m = m0 + ty * 4 + r;
    float4 v = acc[r];
    v.x += bv.x; v.y += bv.y; v.z += bv.z; v.w += bv.w;
    if (add) {
      const float4 d = *(const float4*)&add[m * ldadd + n0 + tx * 4];
      v.x += d.x; v.y += d.y; v.z += d.z; v.w += d.w;
    }
    if (RELU) {
      v.x = fmaxf(v.x, 0.f); v.y = fmaxf(v.y, 0.f);
      v.z = fmaxf(v.z, 0.f); v.w = fmaxf(v.w, 0.f);
    }
    *(float4*)&C[m * ldc + n0 + tx * 4] = v;
  }
}

// ---------------- w2 -> bf16 transpose: w2t[n][k] = bf16(w2[k][n]) ----------
__global__ __launch_bounds__(256)
void w2_transpose(const float* __restrict__ w2, ushort* __restrict__ w2t) {
  __shared__ float t[64][65];
  int k0 = blockIdx.y * 64, n0 = blockIdx.x * 64;
  int tid = threadIdx.x;
  int c = tid & 63, r0 = tid >> 6;
#pragma unroll
  for (int q = 0; q < 16; ++q) {
    int r = r0 + q * 4;
    t[r][c] = w2[(k0 + r) * HH + n0 + c];
  }
  __syncthreads();
#pragma unroll
  for (int q = 0; q < 16; ++q) {
    int r = r0 + q * 4;
    w2t[(n0 + r) * HH + k0 + c] = f2bf(t[c][r]);
  }
}

// ---------------- fused edge MLP ----------------
// Block = 8 i's x 16 j's = 128 pairs; 8 waves, each owns 64 N-cols of layer 2.
// h1 chunk (128 pairs x 128 k, bf16, XOR-swizzled) staged in LDS; layer-2 GEMM
// via mfma 16x16x32 bf16; epilogue: relu(+b2), dot w3, lane reduce, sigmoid.
__global__ __launch_bounds__(512, 2)
void edge_mlp(const float* __restrict__ Amat, const float* __restrict__ Bmat,
              const ushort* __restrict__ w2t,
              const float* __restrict__ b2, const float* __restrict__ w3,
              const float* __restrict__ b3,
              float* __restrict__ edges)
{
  const int bj = blockIdx.x, bi = blockIdx.y;
  if (bi * 8 > bj * 16 + 15) return;  // no pair with i<=j in range

  __shared__ ushort h1s[128 * 128];   // 32 KB, swizzled
  __shared__ float part[8][128];

  const int tid = threadIdx.x;
  const int wid = tid >> 6;
  const int lane = tid & 63;
  const int nbase = wid * 64;
  const int l15 = lane & 15;
  const int lg = lane >> 4;

  const f4v zero = {0.f, 0.f, 0.f, 0.f};
  f4v acc[8][4];
#pragma unroll
  for (int mf = 0; mf < 8; ++mf)
#pragma unroll
    for (int nf = 0; nf < 4; ++nf) acc[mf][nf] = zero;

  for (int ch = 0; ch < 4; ++ch) {
    if (ch) __syncthreads();
    // stage h1 chunk: h1[p][k] = relu(Amat[i(p)][k] + Bmat[j(p)][k]) as bf16
#pragma unroll
    for (int q = 0; q < 8; ++q) {
      int fidx = q * 512 + tid;
      int p = fidx >> 5;
      int k4 = fidx & 31;
      int i = bi * 8 + (p >> 4);
      int j = bj * 16 + (p & 15);
      float4 av = *(const float4*)(Amat + i * HH + ch * 128 + k4 * 4);
      float4 bv = *(const float4*)(Bmat + j * HH + ch * 128 + k4 * 4);
      ushort4 pk;
      pk.x = f2bf(fmaxf(av.x + bv.x, 0.f));
      pk.y = f2bf(fmaxf(av.y + bv.y, 0.f));
      pk.z = f2bf(fmaxf(av.z + bv.z, 0.f));
      pk.w = f2bf(fmaxf(av.w + bv.w, 0.f));
      int off = (p * 256 + k4 * 8) ^ ((p & 7) << 4);
      *(ushort4*)((char*)h1s + off) = pk;
    }
    __syncthreads();
#pragma unroll
    for (int ks = 0; ks < 4; ++ks) {
      s8v bfr[4];
#pragma unroll
      for (int nf = 0; nf < 4; ++nf) {
        int col = nbase + nf * 16 + l15;
        int kk = ch * 128 + ks * 32 + lg * 8;
        bfr[nf] = *(const s8v*)(w2t + col * HH + kk);
      }
      s8v afr[8];
#pragma unroll
      for (int mf = 0; mf < 8; ++mf) {
        int p = mf * 16 + l15;
        int off = (p * 256 + ks * 64 + lg * 16) ^ ((p & 7) << 4);
        afr[mf] = *(const s8v*)((const char*)h1s + off);
      }
#pragma unroll
      for (int mf = 0; mf < 8; ++mf)
#pragma unroll
        for (int nf = 0; nf < 4; ++nf)
          acc[mf][nf] = __builtin_amdgcn_mfma_f32_16x16x32_bf16(
              afr[mf], bfr[nf], acc[mf][nf], 0, 0, 0);
    }
  }

  // epilogue: h2 = relu(acc + b2); partial = sum h2*w3 over this wave's cols
  float bb[4], ww[4];
#pragma unroll
  for (int nf = 0; nf < 4; ++nf) {
    int col = nbase + nf * 16 + l15;
    bb[nf] = b2[col];
    ww[nf] = w3[col];
  }
#pragma unroll
  for (int mf = 0; mf < 8; ++mf) {
    float ps0 = 0.f, ps1 = 0.f, ps2 = 0.f, ps3 = 0.f;
#pragma unroll
    for (int nf = 0; nf < 4; ++nf) {
      f4v v = acc[mf][nf];
      ps0 += fmaxf(v[0] + bb[nf], 0.f) * ww[nf];
      ps1 += fmaxf(v[1] + bb[nf], 0.f) * ww[nf];
      ps2 += fmaxf(v[2] + bb[nf], 0.f) * ww[nf];
      ps3 += fmaxf(v[3] + bb[nf], 0.f) * ww[nf];
    }
#pragma unroll
    for (int m = 1; m < 16; m <<= 1) {
      ps0 += __shfl_xor(ps0, m);
      ps1 += __shfl_xor(ps1, m);
      ps2 += __shfl_xor(ps2, m);
      ps3 += __shfl_xor(ps3, m);
    }
    if (l15 == 0) {
      int pr = mf * 16 + lg * 4;
      part[wid][pr + 0] = ps0;
      part[wid][pr + 1] = ps1;
      part[wid][pr + 2] = ps2;
      part[wid][pr + 3] = ps3;
    }
  }
  __syncthreads();
  if (tid < 128) {
    float tot = b3[0];
#pragma unroll
    for (int w = 0; w < 8; ++w) tot += part[w][tid];
    float sg = 1.f / (1.f + expf(-tot));
    int i = bi * 8 + (tid >> 4);
    int j = bj * 16 + (tid & 15);
    if (i < j) {
      edges[i * NN + j] = sg;
      edges[j * NN + i] = sg;
    } else if (i == j) {
      edges[i * NN + i] = 0.f;
    }
  }
}

extern "C" void kernel_launch(void* const* d_in, const int* in_sizes, int n_in,
                              void* d_out, int out_size, void* d_ws, size_t ws_size,
                              hipStream_t stream) {
  const float* node = (const float*)d_in[0];
  const float* adj  = (const float*)d_in[1];
  const float* g1wl = (const float*)d_in[2];
  const float* g1bl = (const float*)d_in[3];
  const float* g1ws = (const float*)d_in[4];
  const float* g1bs = (const float*)d_in[5];
  const float* g2wl = (const float*)d_in[6];
  const float* g2bl = (const float*)d_in[7];
  const float* g2ws = (const float*)d_in[8];
  const float* g2bs = (const float*)d_in[9];
  const float* g3wl = (const float*)d_in[10];
  const float* g3bl = (const float*)d_in[11];
  const float* g3ws = (const float*)d_in[12];
  const float* g3bs = (const float*)d_in[13];
  const float* w1 = (const float*)d_in[14];
  const float* b1 = (const float*)d_in[15];
  const float* w2 = (const float*)d_in[16];
  const float* b2 = (const float*)d_in[17];
  const float* w3 = (const float*)d_in[18];
  const float* b3 = (const float*)d_in[19];

  float* out = (float*)d_out;
  float* emb = out;                 // [512][256]
  float* edges = out + NN * FF;     // [512][512]

  char* wsb = (char*)d_ws;
  float* adjn = (float*)wsb;                     // 1 MB
  float* Tb   = (float*)(wsb + (1u << 20));      // 1 MB
  float* Sb   = (float*)(wsb + (2u << 20));      // 1 MB
  float* xa   = (float*)(wsb + (3u << 20));      // 1 MB
  float* xb   = (float*)(wsb + (4u << 20));      // 1 MB
  ushort* w2t = (ushort*)(wsb + (5u << 20));     // 512 KB
  float* Amat = Tb;  // reused after GCN
  float* Bmat = Sb;

  // adjacency row-normalize
  rownorm_kernel<<<NN, 256, 0, stream>>>(adj, adjn);
  // w2 transpose+cast (independent)
  w2_transpose<<<dim3(8, 8), 256, 0, stream>>>(w2, w2t);

  // ---- GCN layer 1: T=x@wl+bl, S=x@ws+bs ; xa=relu(adjn@T+S)
  gemm_ts<false><<<dim3(8, 8, 2), 256, 0, stream>>>(
      NN, HH, FF, node, FF, g1wl, g1ws, HH, g1bl, g1bs,
      nullptr, nullptr, 0, Tb, Sb, HH);
  gemm_ts<true><<<dim3(8, 8, 1), 256, 0, stream>>>(
      NN, HH, NN, adjn, NN, Tb, Tb, HH, nullptr, nullptr,
      Sb, Sb, HH, xa, xa, HH);
  // ---- GCN layer 2
  gemm_ts<false><<<dim3(8, 8, 2), 256, 0, stream>>>(
      NN, HH, HH, xa, HH, g2wl, g2ws, HH, g2bl, g2bs,
      nullptr, nullptr, 0, Tb, Sb, HH);
  gemm_ts<true><<<dim3(8, 8, 1), 256, 0, stream>>>(
      NN, HH, NN, adjn, NN, Tb, Tb, HH, nullptr, nullptr,
      Sb, Sb, HH, xb, xb, HH);
  // ---- GCN layer 3 (no relu) -> emb (d_out)
  gemm_ts<false><<<dim3(4, 8, 2), 256, 0, stream>>>(
      NN, FF, HH, xb, HH, g3wl, g3ws, FF, g3bl, g3bs,
      nullptr, nullptr, 0, Tb, Sb, FF);
  gemm_ts<false><<<dim3(4, 8, 1), 256, 0, stream>>>(
      NN, FF, NN, adjn, NN, Tb, Tb, FF, nullptr, nullptr,
      Sb, Sb, FF, emb, emb, FF);

  // ---- edge MLP layer-1 factorization: Amat = emb@w1_top+b1, Bmat = emb@w1_bot
  gemm_ts<false><<<dim3(8, 8, 2), 256, 0, stream>>>(
      NN, HH, FF, emb, FF, w1, w1 + FF * HH, HH, b1, nullptr,
      nullptr, nullptr, 0, Amat, Bmat, HH);

  // ---- fused edge MLP (layer2 MFMA + layer3 + sigmoid + symmetric scatter)
  edge_mlp<<<dim3(32, 64), 512, 0, stream>>>(Amat, Bmat, w2t, b2, w3, b3, edges);
}

// Round 2
// 326.248 us; speedup vs baseline: 1.2391x; 1.2391x over previous
//
#include <hip/hip_runtime.h>
#include <hip/hip_bf16.h>

// GraphNeuralAssociator: GCN(3 layers, fp32) + all-pairs edge MLP.
// Edge MLP layer 1 factorized: h1(i,j) = relu(Amat[i] + Bmat[j]).
// Layer 2 (68.6 GF) = bf16 MFMA 16x16x32, fp32 accum; layer 3 + sigmoid fused.
// v2: 1024-thr blocks (16 waves, 8mf x 2nf = 64 acc regs/wave -> 4 waves/SIMD),
// double-buffered 2x32KB LDS h1, exact triangular grid, contiguous w2 packing.

#define NN 512
#define FF 256
#define HH 512

typedef __attribute__((ext_vector_type(8))) short s8v;   // 8 x bf16 bits
typedef __attribute__((ext_vector_type(4))) float f4v;   // MFMA acc

__device__ __forceinline__ ushort f2bf(float f) {
  unsigned u = __float_as_uint(f);
  unsigned r = (u + 0x7fffu + ((u >> 16) & 1u)) >> 16;
  return (ushort)r;
}

// ---------------- row-normalize adjacency ----------------
__global__ __launch_bounds__(256)
void rownorm_kernel(const float* __restrict__ adj, float* __restrict__ adjn) {
  int row = blockIdx.x;
  int tid = threadIdx.x;
  const float* r = adj + row * NN;
  float a0 = r[tid], a1 = r[tid + 256];
  float s = a0 + a1;
#pragma unroll
  for (int m = 1; m < 64; m <<= 1) s += __shfl_xor(s, m);
  __shared__ float wsum[4];
  if ((tid & 63) == 0) wsum[tid >> 6] = s;
  __syncthreads();
  float inv = 1.f / (wsum[0] + wsum[1] + wsum[2] + wsum[3] + 1e-8f);
  float* o = adjn + row * NN;
  o[tid] = a0 * inv;
  o[tid + 256] = a1 * inv;
}

// ---------------- fp32 GEMM, 32x64 tile, dual-output via z ----------------
// C = [relu]( A@B + bias + add )
template <bool RELU>
__global__ __launch_bounds__(256)
void gemm_ts(int M, int N, int K,
             const float* __restrict__ A, int lda,
             const float* __restrict__ B0, const float* __restrict__ B1, int ldb,
             const float* __restrict__ bias0, const float* __restrict__ bias1,
             const float* __restrict__ add0, const float* __restrict__ add1, int ldadd,
             float* __restrict__ C0, float* __restrict__ C1, int ldc)
{
  const float* B = blockIdx.z ? B1 : B0;
  const float* bias = blockIdx.z ? bias1 : bias0;
  const float* add = blockIdx.z ? add1 : add0;
  float* C = blockIdx.z ? C1 : C0;
  const int n0 = blockIdx.x * 64;
  const int m0 = blockIdx.y * 32;
  const int tid = threadIdx.x;
  const int ty = tid >> 4, tx = tid & 15;

  __shared__ float As[16][34];  // As[k][m], 32 rows
  __shared__ float Bs[16][68];  // Bs[k][n], 64 cols
  float4 acc0 = {0.f, 0.f, 0.f, 0.f};
  float4 acc1 = {0.f, 0.f, 0.f, 0.f};

  for (int k0 = 0; k0 < K; k0 += 16) {
#pragma unroll
    for (int p = 0; p < 2; ++p) {
      int e = tid + p * 256;
      As[e & 15][e >> 4] = A[(m0 + (e >> 4)) * lda + k0 + (e & 15)];
    }
#pragma unroll
    for (int p = 0; p < 4; ++p) {
      int e = tid + p * 256;
      Bs[e >> 6][e & 63] = B[(k0 + (e >> 6)) * ldb + n0 + (e & 63)];
    }
    __syncthreads();
#pragma unroll
    for (int k = 0; k < 16; ++k) {
      float a0 = As[k][ty * 2], a1 = As[k][ty * 2 + 1];
      float4 b = *(const float4*)&Bs[k][tx * 4];
      acc0.x += a0 * b.x; acc0.y += a0 * b.y; acc0.z += a0 * b.z; acc0.w += a0 * b.w;
      acc1.x += a1 * b.x; acc1.y += a1 * b.y; acc1.z += a1 * b.z; acc1.w += a1 * b.w;
    }
    __syncthreads();
  }

  float4 bv = {0.f, 0.f, 0.f, 0.f};
  if (bias) bv = *(const float4*)&bias[n0 + tx * 4];
#pragma unroll
  for (int r = 0; r < 2; ++r) {
    int m = m0 + ty * 2 + r;
    float4 v = r ? acc1 : acc0;
    v.x += bv.x; v.y += bv.y; v.z += bv.z; v.w += bv.w;
    if (add) {
      const float4 d = *(const float4*)&add[m * ldadd + n0 + tx * 4];
      v.x += d.x; v.y += d.y; v.z += d.z; v.w += d.w;
    }
    if (RELU) {
      v.x = fmaxf(v.x, 0.f); v.y = fmaxf(v.y, 0.f);
      v.z = fmaxf(v.z, 0.f); v.w = fmaxf(v.w, 0.f);
    }
    *(float4*)&C[m * ldc + n0 + tx * 4] = v;
  }
}

// ---------------- w2 -> bf16 pack: w2t2[(k>>5)*16384 + col*32 + (k&31)] ------
// Gives fully-contiguous 1KB wave loads for the B fragments of one k-slab.
__global__ __launch_bounds__(256)
void w2_pack(const float* __restrict__ w2, ushort* __restrict__ w2t2) {
  int slab = blockIdx.y;                       // 16 slabs of 32 k
  int col = blockIdx.x * 64 + (threadIdx.x >> 2);
  int kq = threadIdx.x & 3;                    // 8-k sub-block
  int k0 = slab * 32 + kq * 8;
  ushort tmp[8];
#pragma unroll
  for (int e = 0; e < 8; ++e) tmp[e] = f2bf(w2[(k0 + e) * HH + col]);
  ushort* dst = w2t2 + slab * 16384 + col * 32 + kq * 8;
  *(ushort4*)dst = *(ushort4*)tmp;
  *(ushort4*)(dst + 4) = *(ushort4*)&tmp[4];
}

// ---------------- fused edge MLP ----------------
// Block = 8 i's x 16 j's = 128 pairs x all 512 cols. 1024 threads = 16 waves;
// wave w owns cols [32w, 32w+32): 8 mf x 2 nf fragments (64 acc VGPRs).
// K=512 in 4 chunks of 128, double-buffered in LDS (2 x 32 KB, XOR-swizzled).
__global__ __launch_bounds__(1024, 4)
void edge_mlp(const float* __restrict__ Amat, const float* __restrict__ Bmat,
              const ushort* __restrict__ w2t2,
              const float* __restrict__ b2, const float* __restrict__ w3,
              const float* __restrict__ b3,
              float* __restrict__ edges)
{
  __shared__ ushort h1s[2][128 * 128];  // 2 x 32 KB (64 KB total)

  // exact upper-triangle tile decode: tiles before col-block bj = bj^2+bj
  const int tb = (int)blockIdx.x;
  int bj = (int)((sqrtf(4.f * tb + 1.f) - 1.f) * 0.5f);
  while (bj * bj + bj > tb) --bj;
  while ((bj + 1) * (bj + 2) <= tb) ++bj;
  const int bi = tb - bj * bj - bj;

  const int tid = threadIdx.x;
  const int wid = tid >> 6;
  const int lane = tid & 63;
  const int l15 = lane & 15;
  const int lg = lane >> 4;

  const f4v zero = {0.f, 0.f, 0.f, 0.f};
  f4v acc[8][2];
#pragma unroll
  for (int mf = 0; mf < 8; ++mf) {
    acc[mf][0] = zero;
    acc[mf][1] = zero;
  }

  // stage chunk ch into buffer buf: h1[p][k] = relu(A[i(p)][k]+B[j(p)][k]) bf16
  auto stage = [&](int ch, int buf) {
#pragma unroll
    for (int q = 0; q < 4; ++q) {
      int fidx = q * 1024 + tid;
      int p = fidx >> 5;        // pair row 0..127
      int k4 = fidx & 31;       // float4 index within 128-k chunk
      int i = bi * 8 + (p >> 4);
      int j = bj * 16 + (p & 15);
      float4 av = *(const float4*)(Amat + i * HH + ch * 128 + k4 * 4);
      float4 bv = *(const float4*)(Bmat + j * HH + ch * 128 + k4 * 4);
      ushort4 pk;
      pk.x = f2bf(fmaxf(av.x + bv.x, 0.f));
      pk.y = f2bf(fmaxf(av.y + bv.y, 0.f));
      pk.z = f2bf(fmaxf(av.z + bv.z, 0.f));
      pk.w = f2bf(fmaxf(av.w + bv.w, 0.f));
      int off = (p * 256 + k4 * 8) ^ ((p & 7) << 4);
      *(ushort4*)((char*)h1s[buf] + off) = pk;
    }
  };

  stage(0, 0);
  __syncthreads();

  for (int ch = 0; ch < 4; ++ch) {
    int cur = ch & 1;
    if (ch < 3) stage(ch + 1, cur ^ 1);
#pragma unroll
    for (int ks = 0; ks < 4; ++ks) {
      int slab = ch * 4 + ks;
      const ushort* wb = w2t2 + slab * 16384 + wid * 1024 + l15 * 32 + lg * 8;
      s8v b0 = *(const s8v*)wb;
      s8v b1 = *(const s8v*)(wb + 512);
#pragma unroll
      for (int mf = 0; mf < 8; ++mf) {
        int p = mf * 16 + l15;
        int off = (p * 256 + ks * 64 + lg * 16) ^ ((p & 7) << 4);
        s8v a = *(const s8v*)((const char*)h1s[cur] + off);
        acc[mf][0] = __builtin_amdgcn_mfma_f32_16x16x32_bf16(a, b0, acc[mf][0], 0, 0, 0);
        acc[mf][1] = __builtin_amdgcn_mfma_f32_16x16x32_bf16(a, b1, acc[mf][1], 0, 0, 0);
      }
    }
    __syncthreads();
  }

  // epilogue: h2 = relu(acc+b2); partial = h2 . w3 over this wave's 32 cols
  float* part = (float*)&h1s[0][0];  // [16][128], aliases retired LDS
  float bb0 = b2[wid * 32 + l15], bb1 = b2[wid * 32 + 16 + l15];
  float ww0 = w3[wid * 32 + l15], ww1 = w3[wid * 32 + 16 + l15];
#pragma unroll
  for (int mf = 0; mf < 8; ++mf) {
    float ps[4];
#pragma unroll
    for (int e = 0; e < 4; ++e)
      ps[e] = fmaxf(acc[mf][0][e] + bb0, 0.f) * ww0 +
              fmaxf(acc[mf][1][e] + bb1, 0.f) * ww1;
#pragma unroll
    for (int m = 1; m < 16; m <<= 1) {
#pragma unroll
      for (int e = 0; e < 4; ++e) ps[e] += __shfl_xor(ps[e], m);
    }
    if (l15 == 0) {
#pragma unroll
      for (int e = 0; e < 4; ++e)
        part[wid * 128 + mf * 16 + lg * 4 + e] = ps[e];
    }
  }
  __syncthreads();
  if (tid < 128) {
    float tot = b3[0];
#pragma unroll
    for (int w = 0; w < 16; ++w) tot += part[w * 128 + tid];
    float sg = 1.f / (1.f + expf(-tot));
    int i = bi * 8 + (tid >> 4);
    int j = bj * 16 + (tid & 15);
    if (i < j) {
      edges[i * NN + j] = sg;
      edges[j * NN + i] = sg;
    } else if (i == j) {
      edges[i * NN + i] = 0.f;
    }
  }
}

extern "C" void kernel_launch(void* const* d_in, const int* in_sizes, int n_in,
                              void* d_out, int out_size, void* d_ws, size_t ws_size,
                              hipStream_t stream) {
  const float* node = (const float*)d_in[0];
  const float* adj  = (const float*)d_in[1];
  const float* g1wl = (const float*)d_in[2];
  const float* g1bl = (const float*)d_in[3];
  const float* g1ws = (const float*)d_in[4];
  const float* g1bs = (const float*)d_in[5];
  const float* g2wl = (const float*)d_in[6];
  const float* g2bl = (const float*)d_in[7];
  const float* g2ws = (const float*)d_in[8];
  const float* g2bs = (const float*)d_in[9];
  const float* g3wl = (const float*)d_in[10];
  const float* g3bl = (const float*)d_in[11];
  const float* g3ws = (const float*)d_in[12];
  const float* g3bs = (const float*)d_in[13];
  const float* w1 = (const float*)d_in[14];
  const float* b1 = (const float*)d_in[15];
  const float* w2 = (const float*)d_in[16];
  const float* b2 = (const float*)d_in[17];
  const float* w3 = (const float*)d_in[18];
  const float* b3 = (const float*)d_in[19];

  float* out = (float*)d_out;
  float* emb = out;                 // [512][256]
  float* edges = out + NN * FF;     // [512][512]

  char* wsb = (char*)d_ws;
  float* adjn = (float*)wsb;                     // 1 MB
  float* Tb   = (float*)(wsb + (1u << 20));      // 1 MB
  float* Sb   = (float*)(wsb + (2u << 20));      // 1 MB
  float* xa   = (float*)(wsb + (3u << 20));      // 1 MB
  float* xb   = (float*)(wsb + (4u << 20));      // 1 MB
  ushort* w2t2 = (ushort*)(wsb + (5u << 20));    // 512 KB
  float* Amat = Tb;  // reused after GCN
  float* Bmat = Sb;

  rownorm_kernel<<<NN, 256, 0, stream>>>(adj, adjn);
  w2_pack<<<dim3(8, 16), 256, 0, stream>>>(w2, w2t2);

  // ---- GCN layer 1: T=x@wl+bl, S=x@ws+bs ; xa=relu(adjn@T+S)
  gemm_ts<false><<<dim3(8, 16, 2), 256, 0, stream>>>(
      NN, HH, FF, node, FF, g1wl, g1ws, HH, g1bl, g1bs,
      nullptr, nullptr, 0, Tb, Sb, HH);
  gemm_ts<true><<<dim3(8, 16, 1), 256, 0, stream>>>(
      NN, HH, NN, adjn, NN, Tb, Tb, HH, nullptr, nullptr,
      Sb, Sb, HH, xa, xa, HH);
  // ---- GCN layer 2
  gemm_ts<false><<<dim3(8, 16, 2), 256, 0, stream>>>(
      NN, HH, HH, xa, HH, g2wl, g2ws, HH, g2bl, g2bs,
      nullptr, nullptr, 0, Tb, Sb, HH);
  gemm_ts<true><<<dim3(8, 16, 1), 256, 0, stream>>>(
      NN, HH, NN, adjn, NN, Tb, Tb, HH, nullptr, nullptr,
      Sb, Sb, HH, xb, xb, HH);
  // ---- GCN layer 3 (no relu) -> emb (d_out)
  gemm_ts<false><<<dim3(4, 16, 2), 256, 0, stream>>>(
      NN, FF, HH, xb, HH, g3wl, g3ws, FF, g3bl, g3bs,
      nullptr, nullptr, 0, Tb, Sb, FF);
  gemm_ts<false><<<dim3(4, 16, 1), 256, 0, stream>>>(
      NN, FF, NN, adjn, NN, Tb, Tb, FF, nullptr, nullptr,
      Sb, Sb, FF, emb, emb, FF);

  // ---- edge MLP layer-1 factorization: Amat = emb@w1_top+b1, Bmat = emb@w1_bot
  gemm_ts<false><<<dim3(8, 16, 2), 256, 0, stream>>>(
      NN, HH, FF, emb, FF, w1, w1 + FF * HH, HH, b1, nullptr,
      nullptr, nullptr, 0, Amat, Bmat, HH);

  // ---- fused edge MLP: exact triangular grid (32^2 + 32 = 1056 tiles)
  edge_mlp<<<1056, 1024, 0, stream>>>(Amat, Bmat, w2t2, b2, w3, b3, edges);
}

// Round 3
// 278.974 us; speedup vs baseline: 1.4491x; 1.1695x over previous
//
#include <hip/hip_runtime.h>
#include <hip/hip_bf16.h>

// GraphNeuralAssociator: GCN(3 layers, fp32) + all-pairs edge MLP.
// Edge MLP layer 1 factorized: h1(i,j) = relu(Amat[i] + Bmat[j]).
// Layer 2 (68.6 GF) = bf16 MFMA 16x16x32, fp32 accum; layer 3 + sigmoid fused.
// v3: fix CUDA-semantics launch_bounds (v2's (1024,4) = 4 BLOCKS/CU forced a
// 64-VGPR budget -> ~45 spilled regs -> 191 MB scratch writes/dispatch).
// Now (1024,1): 4 waves/SIMD, 128-VGPR budget, no spill.
// GCN GEMMs: global->reg prefetch double-buffer hides staging latency.

#define NN 512
#define FF 256
#define HH 512

typedef __attribute__((ext_vector_type(8))) short s8v;   // 8 x bf16 bits
typedef __attribute__((ext_vector_type(4))) float f4v;   // MFMA acc

__device__ __forceinline__ ushort f2bf(float f) {
  unsigned u = __float_as_uint(f);
  unsigned r = (u + 0x7fffu + ((u >> 16) & 1u)) >> 16;
  return (ushort)r;
}

// ---------------- row-normalize adjacency ----------------
__global__ __launch_bounds__(256)
void rownorm_kernel(const float* __restrict__ adj, float* __restrict__ adjn) {
  int row = blockIdx.x;
  int tid = threadIdx.x;
  const float* r = adj + row * NN;
  float a0 = r[tid], a1 = r[tid + 256];
  float s = a0 + a1;
#pragma unroll
  for (int m = 1; m < 64; m <<= 1) s += __shfl_xor(s, m);
  __shared__ float wsum[4];
  if ((tid & 63) == 0) wsum[tid >> 6] = s;
  __syncthreads();
  float inv = 1.f / (wsum[0] + wsum[1] + wsum[2] + wsum[3] + 1e-8f);
  float* o = adjn + row * NN;
  o[tid] = a0 * inv;
  o[tid + 256] = a1 * inv;
}

// ---------------- fp32 GEMM, 32x64 tile, dual-output via z ----------------
// C = [relu]( A@B + bias + add ); global->reg prefetch double-buffer.
template <bool RELU>
__global__ __launch_bounds__(256)
void gemm_ts(int M, int N, int K,
             const float* __restrict__ A, int lda,
             const float* __restrict__ B0, const float* __restrict__ B1, int ldb,
             const float* __restrict__ bias0, const float* __restrict__ bias1,
             const float* __restrict__ add0, const float* __restrict__ add1, int ldadd,
             float* __restrict__ C0, float* __restrict__ C1, int ldc)
{
  const float* B = blockIdx.z ? B1 : B0;
  const float* bias = blockIdx.z ? bias1 : bias0;
  const float* add = blockIdx.z ? add1 : add0;
  float* C = blockIdx.z ? C1 : C0;
  const int n0 = blockIdx.x * 64;
  const int m0 = blockIdx.y * 32;
  const int tid = threadIdx.x;
  const int ty = tid >> 4, tx = tid & 15;

  __shared__ float As[16][34];  // As[k][m], 32 rows
  __shared__ float Bs[16][68];  // Bs[k][n], 64 cols
  float4 acc0 = {0.f, 0.f, 0.f, 0.f};
  float4 acc1 = {0.f, 0.f, 0.f, 0.f};

  // per-thread staging coordinates
  const int ar = tid >> 4;          // A rows ar, ar+16; col = ak
  const int ak = tid & 15;
  const int bk = tid >> 4;          // B row bk; cols bn..bn+3
  const int bn = (tid & 15) * 4;

  // prefetch chunk 0
  float pa0 = A[(m0 + ar) * lda + ak];
  float pa1 = A[(m0 + ar + 16) * lda + ak];
  float4 pb = *(const float4*)&B[bk * ldb + n0 + bn];

  for (int k0 = 0; k0 < K; k0 += 16) {
    As[ak][ar] = pa0;
    As[ak][ar + 16] = pa1;
    *(float4*)&Bs[bk][bn] = pb;
    __syncthreads();
    if (k0 + 16 < K) {  // issue next-chunk loads; latency hides under FMAs
      pa0 = A[(m0 + ar) * lda + k0 + 16 + ak];
      pa1 = A[(m0 + ar + 16) * lda + k0 + 16 + ak];
      pb = *(const float4*)&B[(k0 + 16 + bk) * ldb + n0 + bn];
    }
#pragma unroll
    for (int k = 0; k < 16; ++k) {
      float2 a = *(const float2*)&As[k][ty * 2];
      float4 b = *(const float4*)&Bs[k][tx * 4];
      acc0.x += a.x * b.x; acc0.y += a.x * b.y; acc0.z += a.x * b.z; acc0.w += a.x * b.w;
      acc1.x += a.y * b.x; acc1.y += a.y * b.y; acc1.z += a.y * b.z; acc1.w += a.y * b.w;
    }
    __syncthreads();
  }

  float4 bv = {0.f, 0.f, 0.f, 0.f};
  if (bias) bv = *(const float4*)&bias[n0 + tx * 4];
#pragma unroll
  for (int r = 0; r < 2; ++r) {
    int m = m0 + ty * 2 + r;
    float4 v = r ? acc1 : acc0;
    v.x += bv.x; v.y += bv.y; v.z += bv.z; v.w += bv.w;
    if (add) {
      const float4 d = *(const float4*)&add[m * ldadd + n0 + tx * 4];
      v.x += d.x; v.y += d.y; v.z += d.z; v.w += d.w;
    }
    if (RELU) {
      v.x = fmaxf(v.x, 0.f); v.y = fmaxf(v.y, 0.f);
      v.z = fmaxf(v.z, 0.f); v.w = fmaxf(v.w, 0.f);
    }
    *(float4*)&C[m * ldc + n0 + tx * 4] = v;
  }
}

// ---------------- w2 -> bf16 pack: w2t2[(k>>5)*16384 + col*32 + (k&31)] ------
__global__ __launch_bounds__(256)
void w2_pack(const float* __restrict__ w2, ushort* __restrict__ w2t2) {
  int slab = blockIdx.y;                       // 16 slabs of 32 k
  int col = blockIdx.x * 64 + (threadIdx.x >> 2);
  int kq = threadIdx.x & 3;                    // 8-k sub-block
  int k0 = slab * 32 + kq * 8;
  ushort tmp[8];
#pragma unroll
  for (int e = 0; e < 8; ++e) tmp[e] = f2bf(w2[(k0 + e) * HH + col]);
  ushort* dst = w2t2 + slab * 16384 + col * 32 + kq * 8;
  *(ushort4*)dst = *(ushort4*)tmp;
  *(ushort4*)(dst + 4) = *(ushort4*)&tmp[4];
}

// ---------------- fused edge MLP ----------------
// Block = 8 i's x 16 j's = 128 pairs x all 512 cols. 1024 threads = 16 waves;
// wave w owns cols [32w, 32w+32): 8 mf x 2 nf fragments (64 acc VGPRs).
// K=512 in 4 chunks of 128, double-buffered in LDS (2 x 32 KB, XOR-swizzled).
// launch_bounds(1024,1): 4 waves/SIMD, 128-VGPR budget (acc 64 + ~50 live).
__global__ __launch_bounds__(1024, 1)
void edge_mlp(const float* __restrict__ Amat, const float* __restrict__ Bmat,
              const ushort* __restrict__ w2t2,
              const float* __restrict__ b2, const float* __restrict__ w3,
              const float* __restrict__ b3,
              float* __restrict__ edges)
{
  __shared__ ushort h1s[2][128 * 128];  // 2 x 32 KB

  // exact upper-triangle tile decode: tiles before col-block bj = bj^2+bj
  const int tb = (int)blockIdx.x;
  int bj = (int)((sqrtf(4.f * tb + 1.f) - 1.f) * 0.5f);
  while (bj * bj + bj > tb) --bj;
  while ((bj + 1) * (bj + 2) <= tb) ++bj;
  const int bi = tb - bj * bj - bj;

  const int tid = threadIdx.x;
  const int wid = tid >> 6;
  const int lane = tid & 63;
  const int l15 = lane & 15;
  const int lg = lane >> 4;

  const f4v zero = {0.f, 0.f, 0.f, 0.f};
  f4v acc[8][2];
#pragma unroll
  for (int mf = 0; mf < 8; ++mf) {
    acc[mf][0] = zero;
    acc[mf][1] = zero;
  }

  auto stage = [&](int ch, int buf) {
#pragma unroll
    for (int q = 0; q < 4; ++q) {
      int fidx = q * 1024 + tid;
      int p = fidx >> 5;        // pair row 0..127
      int k4 = fidx & 31;       // float4 index within 128-k chunk
      int i = bi * 8 + (p >> 4);
      int j = bj * 16 + (p & 15);
      float4 av = *(const float4*)(Amat + i * HH + ch * 128 + k4 * 4);
      float4 bv = *(const float4*)(Bmat + j * HH + ch * 128 + k4 * 4);
      ushort4 pk;
      pk.x = f2bf(fmaxf(av.x + bv.x, 0.f));
      pk.y = f2bf(fmaxf(av.y + bv.y, 0.f));
      pk.z = f2bf(fmaxf(av.z + bv.z, 0.f));
      pk.w = f2bf(fmaxf(av.w + bv.w, 0.f));
      int off = (p * 256 + k4 * 8) ^ ((p & 7) << 4);
      *(ushort4*)((char*)h1s[buf] + off) = pk;
    }
  };

  stage(0, 0);
  __syncthreads();

  for (int ch = 0; ch < 4; ++ch) {
    int cur = ch & 1;
    if (ch < 3) stage(ch + 1, cur ^ 1);
#pragma unroll
    for (int ks = 0; ks < 4; ++ks) {
      int slab = ch * 4 + ks;
      const ushort* wb = w2t2 + slab * 16384 + wid * 1024 + l15 * 32 + lg * 8;
      s8v b0 = *(const s8v*)wb;
      s8v b1 = *(const s8v*)(wb + 512);
#pragma unroll
      for (int mf = 0; mf < 8; ++mf) {
        int p = mf * 16 + l15;
        int off = (p * 256 + ks * 64 + lg * 16) ^ ((p & 7) << 4);
        s8v a = *(const s8v*)((const char*)h1s[cur] + off);
        acc[mf][0] = __builtin_amdgcn_mfma_f32_16x16x32_bf16(a, b0, acc[mf][0], 0, 0, 0);
        acc[mf][1] = __builtin_amdgcn_mfma_f32_16x16x32_bf16(a, b1, acc[mf][1], 0, 0, 0);
      }
    }
    __syncthreads();
  }

  // epilogue: h2 = relu(acc+b2); partial = h2 . w3 over this wave's 32 cols
  float* part = (float*)&h1s[0][0];  // [16][128], aliases retired LDS
  float bb0 = b2[wid * 32 + l15], bb1 = b2[wid * 32 + 16 + l15];
  float ww0 = w3[wid * 32 + l15], ww1 = w3[wid * 32 + 16 + l15];
#pragma unroll
  for (int mf = 0; mf < 8; ++mf) {
    float ps[4];
#pragma unroll
    for (int e = 0; e < 4; ++e)
      ps[e] = fmaxf(acc[mf][0][e] + bb0, 0.f) * ww0 +
              fmaxf(acc[mf][1][e] + bb1, 0.f) * ww1;
#pragma unroll
    for (int m = 1; m < 16; m <<= 1) {
#pragma unroll
      for (int e = 0; e < 4; ++e) ps[e] += __shfl_xor(ps[e], m);
    }
    if (l15 == 0) {
#pragma unroll
      for (int e = 0; e < 4; ++e)
        part[wid * 128 + mf * 16 + lg * 4 + e] = ps[e];
    }
  }
  __syncthreads();
  if (tid < 128) {
    float tot = b3[0];
#pragma unroll
    for (int w = 0; w < 16; ++w) tot += part[w * 128 + tid];
    float sg = 1.f / (1.f + expf(-tot));
    int i = bi * 8 + (tid >> 4);
    int j = bj * 16 + (tid & 15);
    if (i < j) {
      edges[i * NN + j] = sg;
      edges[j * NN + i] = sg;
    } else if (i == j) {
      edges[i * NN + i] = 0.f;
    }
  }
}

extern "C" void kernel_launch(void* const* d_in, const int* in_sizes, int n_in,
                              void* d_out, int out_size, void* d_ws, size_t ws_size,
                              hipStream_t stream) {
  const float* node = (const float*)d_in[0];
  const float* adj  = (const float*)d_in[1];
  const float* g1wl = (const float*)d_in[2];
  const float* g1bl = (const float*)d_in[3];
  const float* g1ws = (const float*)d_in[4];
  const float* g1bs = (const float*)d_in[5];
  const float* g2wl = (const float*)d_in[6];
  const float* g2bl = (const float*)d_in[7];
  const float* g2ws = (const float*)d_in[8];
  const float* g2bs = (const float*)d_in[9];
  const float* g3wl = (const float*)d_in[10];
  const float* g3bl = (const float*)d_in[11];
  const float* g3ws = (const float*)d_in[12];
  const float* g3bs = (const float*)d_in[13];
  const float* w1 = (const float*)d_in[14];
  const float* b1 = (const float*)d_in[15];
  const float* w2 = (const float*)d_in[16];
  const float* b2 = (const float*)d_in[17];
  const float* w3 = (const float*)d_in[18];
  const float* b3 = (const float*)d_in[19];

  float* out = (float*)d_out;
  float* emb = out;                 // [512][256]
  float* edges = out + NN * FF;     // [512][512]

  char* wsb = (char*)d_ws;
  float* adjn = (float*)wsb;                     // 1 MB
  float* Tb   = (float*)(wsb + (1u << 20));      // 1 MB
  float* Sb   = (float*)(wsb + (2u << 20));      // 1 MB
  float* xa   = (float*)(wsb + (3u << 20));      // 1 MB
  float* xb   = (float*)(wsb + (4u << 20));      // 1 MB
  ushort* w2t2 = (ushort*)(wsb + (5u << 20));    // 512 KB
  float* Amat = Tb;  // reused after GCN
  float* Bmat = Sb;

  rownorm_kernel<<<NN, 256, 0, stream>>>(adj, adjn);
  w2_pack<<<dim3(8, 16), 256, 0, stream>>>(w2, w2t2);

  // ---- GCN layer 1: T=x@wl+bl, S=x@ws+bs ; xa=relu(adjn@T+S)
  gemm_ts<false><<<dim3(8, 16, 2), 256, 0, stream>>>(
      NN, HH, FF, node, FF, g1wl, g1ws, HH, g1bl, g1bs,
      nullptr, nullptr, 0, Tb, Sb, HH);
  gemm_ts<true><<<dim3(8, 16, 1), 256, 0, stream>>>(
      NN, HH, NN, adjn, NN, Tb, Tb, HH, nullptr, nullptr,
      Sb, Sb, HH, xa, xa, HH);
  // ---- GCN layer 2
  gemm_ts<false><<<dim3(8, 16, 2), 256, 0, stream>>>(
      NN, HH, HH, xa, HH, g2wl, g2ws, HH, g2bl, g2bs,
      nullptr, nullptr, 0, Tb, Sb, HH);
  gemm_ts<true><<<dim3(8, 16, 1), 256, 0, stream>>>(
      NN, HH, NN, adjn, NN, Tb, Tb, HH, nullptr, nullptr,
      Sb, Sb, HH, xb, xb, HH);
  // ---- GCN layer 3 (no relu) -> emb (d_out)
  gemm_ts<false><<<dim3(4, 16, 2), 256, 0, stream>>>(
      NN, FF, HH, xb, HH, g3wl, g3ws, FF, g3bl, g3bs,
      nullptr, nullptr, 0, Tb, Sb, FF);
  gemm_ts<false><<<dim3(4, 16, 1), 256, 0, stream>>>(
      NN, FF, NN, adjn, NN, Tb, Tb, FF, nullptr, nullptr,
      Sb, Sb, FF, emb, emb, FF);

  // ---- edge MLP layer-1 factorization: Amat = emb@w1_top+b1, Bmat = emb@w1_bot
  gemm_ts<false><<<dim3(8, 16, 2), 256, 0, stream>>>(
      NN, HH, FF, emb, FF, w1, w1 + FF * HH, HH, b1, nullptr,
      nullptr, nullptr, 0, Amat, Bmat, HH);

  // ---- fused edge MLP: exact triangular grid (32^2 + 32 = 1056 tiles)
  edge_mlp<<<1056, 1024, 0, stream>>>(Amat, Bmat, w2t2, b2, w3, b3, edges);
}

// Round 4
// 208.020 us; speedup vs baseline: 1.9433x; 1.3411x over previous
//
#include <hip/hip_runtime.h>
#include <hip/hip_bf16.h>

// GraphNeuralAssociator: GCN(3 layers, fp32) + all-pairs edge MLP.
// Edge MLP layer 1 factorized: h1(i,j) = relu(Amat[i] + Bmat[j]).
// Layer 2 (68.6 GF) = bf16 MFMA 16x16x32, fp32 accum; layer 3 + sigmoid fused.
// v4: 1024-thread blocks hard-cap total regs at 128/thread (4 waves/SIMD of
// the same block; 512-reg pool/SIMD) -> v2/v3's 64-acc kernel force-spilled
// ~46 arch regs (191 MB scratch writes). Back to 512-thr/8-wave blocks:
// 2 waves/EU budget = 256 regs; acc[8][4]=128 AGPR + ~80 arch fits. LDS
// padded to 84KB so only 1 block/CU (prevents a 2-block/CU regalloc target),
// plus amdgpu_waves_per_eu(2,2). Double-buffered h1, w2 reg-prefetch per ks.

#define NN 512
#define FF 256
#define HH 512

typedef __attribute__((ext_vector_type(8))) short s8v;   // 8 x bf16 bits
typedef __attribute__((ext_vector_type(4))) float f4v;   // MFMA acc

__device__ __forceinline__ ushort f2bf(float f) {
  unsigned u = __float_as_uint(f);
  unsigned r = (u + 0x7fffu + ((u >> 16) & 1u)) >> 16;
  return (ushort)r;
}

// ---------------- row-normalize adjacency ----------------
__global__ __launch_bounds__(256)
void rownorm_kernel(const float* __restrict__ adj, float* __restrict__ adjn) {
  int row = blockIdx.x;
  int tid = threadIdx.x;
  const float* r = adj + row * NN;
  float a0 = r[tid], a1 = r[tid + 256];
  float s = a0 + a1;
#pragma unroll
  for (int m = 1; m < 64; m <<= 1) s += __shfl_xor(s, m);
  __shared__ float wsum[4];
  if ((tid & 63) == 0) wsum[tid >> 6] = s;
  __syncthreads();
  float inv = 1.f / (wsum[0] + wsum[1] + wsum[2] + wsum[3] + 1e-8f);
  float* o = adjn + row * NN;
  o[tid] = a0 * inv;
  o[tid + 256] = a1 * inv;
}

// ---------------- fp32 GEMM, 16x64 tile, BK=32, dual-output via z ----------
// C = [relu]( A@B + bias + add ); global->reg prefetch double-buffer.
template <bool RELU>
__global__ __launch_bounds__(256)
void gemm_ts(int M, int N, int K,
             const float* __restrict__ A, int lda,
             const float* __restrict__ B0, const float* __restrict__ B1, int ldb,
             const float* __restrict__ bias0, const float* __restrict__ bias1,
             const float* __restrict__ add0, const float* __restrict__ add1, int ldadd,
             float* __restrict__ C0, float* __restrict__ C1, int ldc)
{
  const float* B = blockIdx.z ? B1 : B0;
  const float* bias = blockIdx.z ? bias1 : bias0;
  const float* add = blockIdx.z ? add1 : add0;
  float* C = blockIdx.z ? C1 : C0;
  const int n0 = blockIdx.x * 64;
  const int m0 = blockIdx.y * 16;
  const int tid = threadIdx.x;
  const int ty = tid >> 4, tx = tid & 15;

  __shared__ float As[32][18];  // [k][m]
  __shared__ float Bs[32][68];  // [k][n]
  float4 acc = {0.f, 0.f, 0.f, 0.f};

  const int am = tid >> 4;      // A row 0..15
  const int ak = tid & 15;      // k float2 index
  const int bk = tid >> 4;      // B rows bk, bk+16
  const int bn = tid & 15;      // col float4 index

  float2 pa = *(const float2*)&A[(m0 + am) * lda + ak * 2];
  float4 pb0 = *(const float4*)&B[bk * ldb + n0 + bn * 4];
  float4 pb1 = *(const float4*)&B[(bk + 16) * ldb + n0 + bn * 4];

  for (int k0 = 0; k0 < K; k0 += 32) {
    As[ak * 2][am] = pa.x;
    As[ak * 2 + 1][am] = pa.y;
    *(float4*)&Bs[bk][bn * 4] = pb0;
    *(float4*)&Bs[bk + 16][bn * 4] = pb1;
    __syncthreads();
    if (k0 + 32 < K) {  // next-chunk loads hide under FMAs
      pa = *(const float2*)&A[(m0 + am) * lda + k0 + 32 + ak * 2];
      pb0 = *(const float4*)&B[(k0 + 32 + bk) * ldb + n0 + bn * 4];
      pb1 = *(const float4*)&B[(k0 + 48 + bk) * ldb + n0 + bn * 4];
    }
#pragma unroll
    for (int k = 0; k < 32; ++k) {
      float a = As[k][ty];
      float4 b = *(const float4*)&Bs[k][tx * 4];
      acc.x += a * b.x; acc.y += a * b.y; acc.z += a * b.z; acc.w += a * b.w;
    }
    __syncthreads();
  }

  int m = m0 + ty;
  float4 v = acc;
  if (bias) {
    float4 bv = *(const float4*)&bias[n0 + tx * 4];
    v.x += bv.x; v.y += bv.y; v.z += bv.z; v.w += bv.w;
  }
  if (add) {
    float4 d = *(const float4*)&add[m * ldadd + n0 + tx * 4];
    v.x += d.x; v.y += d.y; v.z += d.z; v.w += d.w;
  }
  if (RELU) {
    v.x = fmaxf(v.x, 0.f); v.y = fmaxf(v.y, 0.f);
    v.z = fmaxf(v.z, 0.f); v.w = fmaxf(v.w, 0.f);
  }
  *(float4*)&C[m * ldc + n0 + tx * 4] = v;
}

// ---------------- w2 -> bf16 pack: w2t2[(k>>5)*16384 + col*32 + (k&31)] ------
__global__ __launch_bounds__(256)
void w2_pack(const float* __restrict__ w2, ushort* __restrict__ w2t2) {
  int slab = blockIdx.y;                       // 16 slabs of 32 k
  int col = blockIdx.x * 64 + (threadIdx.x >> 2);
  int kq = threadIdx.x & 3;                    // 8-k sub-block
  int k0 = slab * 32 + kq * 8;
  ushort tmp[8];
#pragma unroll
  for (int e = 0; e < 8; ++e) tmp[e] = f2bf(w2[(k0 + e) * HH + col]);
  ushort* dst = w2t2 + slab * 16384 + col * 32 + kq * 8;
  *(ushort4*)dst = *(ushort4*)tmp;
  *(ushort4*)(dst + 4) = *(ushort4*)&tmp[4];
}

// ---------------- fused edge MLP ----------------
// Block = 8 i's x 16 j's = 128 pairs x all 512 cols. 512 threads = 8 waves;
// wave w owns cols [64w, 64w+64): 8 mf x 4 nf fragments (128 acc regs).
// K=512 in 4 chunks of 128, double-buffered LDS (2 x 32 KB, XOR-swizzled).
// LDS padded to 84KB -> 1 block/CU -> 256-reg/thread budget (no spill).
__global__ __launch_bounds__(512)
__attribute__((amdgpu_waves_per_eu(2, 2)))
void edge_mlp(const float* __restrict__ Amat, const float* __restrict__ Bmat,
              const ushort* __restrict__ w2t2,
              const float* __restrict__ b2, const float* __restrict__ w3,
              const float* __restrict__ b3,
              float* __restrict__ edges)
{
  __shared__ ushort h1s[2][128 * 128];  // 64 KB
  __shared__ float part[8][640];        // 20 KB (only [8][128] used; pads LDS)

  // exact upper-triangle tile decode: tiles before col-block bj = bj^2+bj
  const int tb = (int)blockIdx.x;
  int bj = (int)((sqrtf(4.f * tb + 1.f) - 1.f) * 0.5f);
  while (bj * bj + bj > tb) --bj;
  while ((bj + 1) * (bj + 2) <= tb) ++bj;
  const int bi = tb - bj * bj - bj;

  const int tid = threadIdx.x;
  const int wid = tid >> 6;
  const int lane = tid & 63;
  const int l15 = lane & 15;
  const int lg = lane >> 4;

  const f4v zero = {0.f, 0.f, 0.f, 0.f};
  f4v acc[8][4];
#pragma unroll
  for (int mf = 0; mf < 8; ++mf)
#pragma unroll
    for (int nf = 0; nf < 4; ++nf) acc[mf][nf] = zero;

  // stage chunk ch: h1[p][k] = relu(A[i(p)][k]+B[j(p)][k]) bf16, swizzled
  auto stage = [&](int ch, int buf) {
#pragma unroll 2
    for (int q = 0; q < 8; ++q) {
      int fidx = q * 512 + tid;
      int p = fidx >> 5;        // pair row 0..127
      int k4 = fidx & 31;       // float4 index within 128-k chunk
      int i = bi * 8 + (p >> 4);
      int j = bj * 16 + (p & 15);
      float4 av = *(const float4*)(Amat + i * HH + ch * 128 + k4 * 4);
      float4 bv = *(const float4*)(Bmat + j * HH + ch * 128 + k4 * 4);
      ushort4 pk;
      pk.x = f2bf(fmaxf(av.x + bv.x, 0.f));
      pk.y = f2bf(fmaxf(av.y + bv.y, 0.f));
      pk.z = f2bf(fmaxf(av.z + bv.z, 0.f));
      pk.w = f2bf(fmaxf(av.w + bv.w, 0.f));
      int off = (p * 256 + k4 * 8) ^ ((p & 7) << 4);
      *(ushort4*)((char*)h1s[buf] + off) = pk;
    }
  };

  stage(0, 0);
  __syncthreads();

  // wave's w2 base: cols [64*wid ..), lane l15 col, lane-group lg k-offset
  const ushort* wbase = w2t2 + wid * 2048 + l15 * 32 + lg * 8;

  for (int ch = 0; ch < 4; ++ch) {
    int cur = ch & 1;
    if (ch < 3) stage(ch + 1, cur ^ 1);
    s8v nb0, nb1, nb2, nb3;
    {
      const ushort* wb = wbase + (ch * 4) * 16384;
      nb0 = *(const s8v*)wb;
      nb1 = *(const s8v*)(wb + 512);
      nb2 = *(const s8v*)(wb + 1024);
      nb3 = *(const s8v*)(wb + 1536);
    }
#pragma unroll
    for (int ks = 0; ks < 4; ++ks) {
      s8v cb0 = nb0, cb1 = nb1, cb2 = nb2, cb3 = nb3;
      if (ks < 3) {  // prefetch next ks slab; wait lands after MFMAs
        const ushort* wb = wbase + (ch * 4 + ks + 1) * 16384;
        nb0 = *(const s8v*)wb;
        nb1 = *(const s8v*)(wb + 512);
        nb2 = *(const s8v*)(wb + 1024);
        nb3 = *(const s8v*)(wb + 1536);
      }
#pragma unroll
      for (int mf = 0; mf < 8; ++mf) {
        int p = mf * 16 + l15;
        int off = (p * 256 + ks * 64 + lg * 16) ^ ((p & 7) << 4);
        s8v a = *(const s8v*)((const char*)h1s[cur] + off);
        acc[mf][0] = __builtin_amdgcn_mfma_f32_16x16x32_bf16(a, cb0, acc[mf][0], 0, 0, 0);
        acc[mf][1] = __builtin_amdgcn_mfma_f32_16x16x32_bf16(a, cb1, acc[mf][1], 0, 0, 0);
        acc[mf][2] = __builtin_amdgcn_mfma_f32_16x16x32_bf16(a, cb2, acc[mf][2], 0, 0, 0);
        acc[mf][3] = __builtin_amdgcn_mfma_f32_16x16x32_bf16(a, cb3, acc[mf][3], 0, 0, 0);
      }
    }
    __syncthreads();
  }

  // epilogue: h2 = relu(acc+b2); partial = h2 . w3 over this wave's 64 cols
  float bb[4], ww[4];
#pragma unroll
  for (int nf = 0; nf < 4; ++nf) {
    int col = wid * 64 + nf * 16 + l15;
    bb[nf] = b2[col];
    ww[nf] = w3[col];
  }
#pragma unroll
  for (int mf = 0; mf < 8; ++mf) {
    float ps[4];
#pragma unroll
    for (int e = 0; e < 4; ++e) {
      ps[e] = fmaxf(acc[mf][0][e] + bb[0], 0.f) * ww[0] +
              fmaxf(acc[mf][1][e] + bb[1], 0.f) * ww[1] +
              fmaxf(acc[mf][2][e] + bb[2], 0.f) * ww[2] +
              fmaxf(acc[mf][3][e] + bb[3], 0.f) * ww[3];
    }
#pragma unroll
    for (int m = 1; m < 16; m <<= 1) {
#pragma unroll
      for (int e = 0; e < 4; ++e) ps[e] += __shfl_xor(ps[e], m);
    }
    if (l15 == 0) {
#pragma unroll
      for (int e = 0; e < 4; ++e)
        part[wid][mf * 16 + lg * 4 + e] = ps[e];
    }
  }
  __syncthreads();
  if (tid < 128) {
    float tot = b3[0];
#pragma unroll
    for (int w = 0; w < 8; ++w) tot += part[w][tid];
    float sg = 1.f / (1.f + expf(-tot));
    int i = bi * 8 + (tid >> 4);
    int j = bj * 16 + (tid & 15);
    if (i < j) {
      edges[i * NN + j] = sg;
      edges[j * NN + i] = sg;
    } else if (i == j) {
      edges[i * NN + i] = 0.f;
    }
  }
}

extern "C" void kernel_launch(void* const* d_in, const int* in_sizes, int n_in,
                              void* d_out, int out_size, void* d_ws, size_t ws_size,
                              hipStream_t stream) {
  const float* node = (const float*)d_in[0];
  const float* adj  = (const float*)d_in[1];
  const float* g1wl = (const float*)d_in[2];
  const float* g1bl = (const float*)d_in[3];
  const float* g1ws = (const float*)d_in[4];
  const float* g1bs = (const float*)d_in[5];
  const float* g2wl = (const float*)d_in[6];
  const float* g2bl = (const float*)d_in[7];
  const float* g2ws = (const float*)d_in[8];
  const float* g2bs = (const float*)d_in[9];
  const float* g3wl = (const float*)d_in[10];
  const float* g3bl = (const float*)d_in[11];
  const float* g3ws = (const float*)d_in[12];
  const float* g3bs = (const float*)d_in[13];
  const float* w1 = (const float*)d_in[14];
  const float* b1 = (const float*)d_in[15];
  const float* w2 = (const float*)d_in[16];
  const float* b2 = (const float*)d_in[17];
  const float* w3 = (const float*)d_in[18];
  const float* b3 = (const float*)d_in[19];

  float* out = (float*)d_out;
  float* emb = out;                 // [512][256]
  float* edges = out + NN * FF;     // [512][512]

  char* wsb = (char*)d_ws;
  float* adjn = (float*)wsb;                     // 1 MB
  float* Tb   = (float*)(wsb + (1u << 20));      // 1 MB
  float* Sb   = (float*)(wsb + (2u << 20));      // 1 MB
  float* xa   = (float*)(wsb + (3u << 20));      // 1 MB
  float* xb   = (float*)(wsb + (4u << 20));      // 1 MB
  ushort* w2t2 = (ushort*)(wsb + (5u << 20));    // 512 KB
  float* Amat = Tb;  // reused after GCN
  float* Bmat = Sb;

  rownorm_kernel<<<NN, 256, 0, stream>>>(adj, adjn);
  w2_pack<<<dim3(8, 16), 256, 0, stream>>>(w2, w2t2);

  // ---- GCN layer 1: T=x@wl+bl, S=x@ws+bs ; xa=relu(adjn@T+S)
  gemm_ts<false><<<dim3(8, 32, 2), 256, 0, stream>>>(
      NN, HH, FF, node, FF, g1wl, g1ws, HH, g1bl, g1bs,
      nullptr, nullptr, 0, Tb, Sb, HH);
  gemm_ts<true><<<dim3(8, 32, 1), 256, 0, stream>>>(
      NN, HH, NN, adjn, NN, Tb, Tb, HH, nullptr, nullptr,
      Sb, Sb, HH, xa, xa, HH);
  // ---- GCN layer 2
  gemm_ts<false><<<dim3(8, 32, 2), 256, 0, stream>>>(
      NN, HH, HH, xa, HH, g2wl, g2ws, HH, g2bl, g2bs,
      nullptr, nullptr, 0, Tb, Sb, HH);
  gemm_ts<true><<<dim3(8, 32, 1), 256, 0, stream>>>(
      NN, HH, NN, adjn, NN, Tb, Tb, HH, nullptr, nullptr,
      Sb, Sb, HH, xb, xb, HH);
  // ---- GCN layer 3 (no relu) -> emb (d_out)
  gemm_ts<false><<<dim3(4, 32, 2), 256, 0, stream>>>(
      NN, FF, HH, xb, HH, g3wl, g3ws, FF, g3bl, g3bs,
      nullptr, nullptr, 0, Tb, Sb, FF);
  gemm_ts<false><<<dim3(4, 32, 1), 256, 0, stream>>>(
      NN, FF, NN, adjn, NN, Tb, Tb, FF, nullptr, nullptr,
      Sb, Sb, FF, emb, emb, FF);

  // ---- edge MLP layer-1 factorization: Amat = emb@w1_top+b1, Bmat = emb@w1_bot
  gemm_ts<false><<<dim3(8, 32, 2), 256, 0, stream>>>(
      NN, HH, FF, emb, FF, w1, w1 + FF * HH, HH, b1, nullptr,
      nullptr, nullptr, 0, Amat, Bmat, HH);

  // ---- fused edge MLP: exact triangular grid (32^2 + 32 = 1056 tiles)
  edge_mlp<<<1056, 512, 0, stream>>>(Amat, Bmat, w2t2, b2, w3, b3, edges);
}

// Round 5
// 194.267 us; speedup vs baseline: 2.0809x; 1.0708x over previous
//
#include <hip/hip_runtime.h>
#include <hip/hip_bf16.h>

// GraphNeuralAssociator: GCN(3 layers, fp32) + all-pairs edge MLP.
// Edge MLP layer 1 factorized: h1(i,j) = relu(Amat[i] + Bmat[j]).
// Layer 2 (68.6 GF) = bf16 MFMA 16x16x32, fp32 accum; layer 3 + sigmoid fused.
// v5: T14 async-STAGE split in edge_mlp. v4 did load->wait->LDS-write BEFORE
// each chunk's MFMAs (L2 latency exposed at every chunk top with only
// 2 waves/SIMD). Now: issue loads into regs early, MFMA slabs, then
// cvt+write late (counted vmcnt); stage split in two 4-q halves (32 regs);
// w2 prefetch rolls across chunk boundaries.

#define NN 512
#define FF 256
#define HH 512

typedef __attribute__((ext_vector_type(8))) short s8v;   // 8 x bf16 bits
typedef __attribute__((ext_vector_type(4))) float f4v;   // MFMA acc

__device__ __forceinline__ ushort f2bf(float f) {
  unsigned u = __float_as_uint(f);
  unsigned r = (u + 0x7fffu + ((u >> 16) & 1u)) >> 16;
  return (ushort)r;
}

// ---------------- row-normalize adjacency ----------------
__global__ __launch_bounds__(256)
void rownorm_kernel(const float* __restrict__ adj, float* __restrict__ adjn) {
  int row = blockIdx.x;
  int tid = threadIdx.x;
  const float* r = adj + row * NN;
  float a0 = r[tid], a1 = r[tid + 256];
  float s = a0 + a1;
#pragma unroll
  for (int m = 1; m < 64; m <<= 1) s += __shfl_xor(s, m);
  __shared__ float wsum[4];
  if ((tid & 63) == 0) wsum[tid >> 6] = s;
  __syncthreads();
  float inv = 1.f / (wsum[0] + wsum[1] + wsum[2] + wsum[3] + 1e-8f);
  float* o = adjn + row * NN;
  o[tid] = a0 * inv;
  o[tid + 256] = a1 * inv;
}

// ---------------- fp32 GEMM, 16x64 tile, BK=32, dual-output via z ----------
template <bool RELU>
__global__ __launch_bounds__(256)
void gemm_ts(int M, int N, int K,
             const float* __restrict__ A, int lda,
             const float* __restrict__ B0, const float* __restrict__ B1, int ldb,
             const float* __restrict__ bias0, const float* __restrict__ bias1,
             const float* __restrict__ add0, const float* __restrict__ add1, int ldadd,
             float* __restrict__ C0, float* __restrict__ C1, int ldc)
{
  const float* B = blockIdx.z ? B1 : B0;
  const float* bias = blockIdx.z ? bias1 : bias0;
  const float* add = blockIdx.z ? add1 : add0;
  float* C = blockIdx.z ? C1 : C0;
  const int n0 = blockIdx.x * 64;
  const int m0 = blockIdx.y * 16;
  const int tid = threadIdx.x;
  const int ty = tid >> 4, tx = tid & 15;

  __shared__ float As[32][18];  // [k][m]
  __shared__ float Bs[32][68];  // [k][n]
  float4 acc = {0.f, 0.f, 0.f, 0.f};

  const int am = tid >> 4;      // A row 0..15
  const int ak = tid & 15;      // k float2 index
  const int bk = tid >> 4;      // B rows bk, bk+16
  const int bn = tid & 15;      // col float4 index

  float2 pa = *(const float2*)&A[(m0 + am) * lda + ak * 2];
  float4 pb0 = *(const float4*)&B[bk * ldb + n0 + bn * 4];
  float4 pb1 = *(const float4*)&B[(bk + 16) * ldb + n0 + bn * 4];

  for (int k0 = 0; k0 < K; k0 += 32) {
    As[ak * 2][am] = pa.x;
    As[ak * 2 + 1][am] = pa.y;
    *(float4*)&Bs[bk][bn * 4] = pb0;
    *(float4*)&Bs[bk + 16][bn * 4] = pb1;
    __syncthreads();
    if (k0 + 32 < K) {  // next-chunk loads hide under FMAs
      pa = *(const float2*)&A[(m0 + am) * lda + k0 + 32 + ak * 2];
      pb0 = *(const float4*)&B[(k0 + 32 + bk) * ldb + n0 + bn * 4];
      pb1 = *(const float4*)&B[(k0 + 48 + bk) * ldb + n0 + bn * 4];
    }
#pragma unroll
    for (int k = 0; k < 32; ++k) {
      float a = As[k][ty];
      float4 b = *(const float4*)&Bs[k][tx * 4];
      acc.x += a * b.x; acc.y += a * b.y; acc.z += a * b.z; acc.w += a * b.w;
    }
    __syncthreads();
  }

  int m = m0 + ty;
  float4 v = acc;
  if (bias) {
    float4 bv = *(const float4*)&bias[n0 + tx * 4];
    v.x += bv.x; v.y += bv.y; v.z += bv.z; v.w += bv.w;
  }
  if (add) {
    float4 d = *(const float4*)&add[m * ldadd + n0 + tx * 4];
    v.x += d.x; v.y += d.y; v.z += d.z; v.w += d.w;
  }
  if (RELU) {
    v.x = fmaxf(v.x, 0.f); v.y = fmaxf(v.y, 0.f);
    v.z = fmaxf(v.z, 0.f); v.w = fmaxf(v.w, 0.f);
  }
  *(float4*)&C[m * ldc + n0 + tx * 4] = v;
}

// ---------------- w2 -> bf16 pack: w2t2[(k>>5)*16384 + col*32 + (k&31)] ------
__global__ __launch_bounds__(256)
void w2_pack(const float* __restrict__ w2, ushort* __restrict__ w2t2) {
  int slab = blockIdx.y;                       // 16 slabs of 32 k
  int col = blockIdx.x * 64 + (threadIdx.x >> 2);
  int kq = threadIdx.x & 3;                    // 8-k sub-block
  int k0 = slab * 32 + kq * 8;
  ushort tmp[8];
#pragma unroll
  for (int e = 0; e < 8; ++e) tmp[e] = f2bf(w2[(k0 + e) * HH + col]);
  ushort* dst = w2t2 + slab * 16384 + col * 32 + kq * 8;
  *(ushort4*)dst = *(ushort4*)tmp;
  *(ushort4*)(dst + 4) = *(ushort4*)&tmp[4];
}

// ---------------- fused edge MLP ----------------
// Block = 8 i's x 16 j's = 128 pairs x all 512 cols. 512 threads = 8 waves;
// wave w owns cols [64w, 64w+64): 8 mf x 4 nf fragments (128 acc regs).
// K=512 in 4 chunks of 128, double-buffered LDS (2 x 32 KB, XOR-swizzled).
// LDS padded to 84KB -> 1 block/CU -> 256-reg/thread budget (no spill).
// T14: issue next-chunk loads early, write LDS late (after MFMA slabs).
__global__ __launch_bounds__(512)
__attribute__((amdgpu_waves_per_eu(2, 2)))
void edge_mlp(const float* __restrict__ Amat, const float* __restrict__ Bmat,
              const ushort* __restrict__ w2t2,
              const float* __restrict__ b2, const float* __restrict__ w3,
              const float* __restrict__ b3,
              float* __restrict__ edges)
{
  __shared__ ushort h1s[2][128 * 128];  // 64 KB
  __shared__ float part[8][640];        // 20 KB (only [8][128] used; pads LDS)

  // exact upper-triangle tile decode: tiles before col-block bj = bj^2+bj
  const int tb = (int)blockIdx.x;
  int bj = (int)((sqrtf(4.f * tb + 1.f) - 1.f) * 0.5f);
  while (bj * bj + bj > tb) --bj;
  while ((bj + 1) * (bj + 2) <= tb) ++bj;
  const int bi = tb - bj * bj - bj;

  const int tid = threadIdx.x;
  const int wid = tid >> 6;
  const int lane = tid & 63;
  const int l15 = lane & 15;
  const int lg = lane >> 4;

  const f4v zero = {0.f, 0.f, 0.f, 0.f};
  f4v acc[8][4];
#pragma unroll
  for (int mf = 0; mf < 8; ++mf)
#pragma unroll
    for (int nf = 0; nf < 4; ++nf) acc[mf][nf] = zero;

  // ---- staged registers (half = 4 q-iters = 32 VGPRs) ----
  float4 sa[4], sb[4];
  auto issue_half = [&](int ch, int h) {  // issue global loads only
#pragma unroll
    for (int q = 0; q < 4; ++q) {
      int fidx = (h * 4 + q) * 512 + tid;
      int p = fidx >> 5;        // pair row 0..127
      int k4 = fidx & 31;       // float4 index within 128-k chunk
      int i = bi * 8 + (p >> 4);
      int j = bj * 16 + (p & 15);
      sa[q] = *(const float4*)(Amat + i * HH + ch * 128 + k4 * 4);
      sb[q] = *(const float4*)(Bmat + j * HH + ch * 128 + k4 * 4);
    }
  };
  auto write_half = [&](int buf, int h) {  // cvt + LDS write (waits on loads)
#pragma unroll
    for (int q = 0; q < 4; ++q) {
      int fidx = (h * 4 + q) * 512 + tid;
      int p = fidx >> 5;
      int k4 = fidx & 31;
      ushort4 pk;
      pk.x = f2bf(fmaxf(sa[q].x + sb[q].x, 0.f));
      pk.y = f2bf(fmaxf(sa[q].y + sb[q].y, 0.f));
      pk.z = f2bf(fmaxf(sa[q].z + sb[q].z, 0.f));
      pk.w = f2bf(fmaxf(sa[q].w + sb[q].w, 0.f));
      int off = (p * 256 + k4 * 8) ^ ((p & 7) << 4);
      *(ushort4*)((char*)h1s[buf] + off) = pk;
    }
  };

  // prologue: stage chunk 0 into buf 0
  issue_half(0, 0); write_half(0, 0);
  issue_half(0, 1); write_half(0, 1);
  __syncthreads();

  // wave's w2 base: cols [64*wid ..), lane l15 col, lane-group lg k-offset
  const ushort* wbase = w2t2 + wid * 2048 + l15 * 32 + lg * 8;

  // rolling w2 prefetch (one 32-k slab ahead, across chunk boundaries)
  s8v nb0, nb1, nb2, nb3;
  nb0 = *(const s8v*)wbase;
  nb1 = *(const s8v*)(wbase + 512);
  nb2 = *(const s8v*)(wbase + 1024);
  nb3 = *(const s8v*)(wbase + 1536);

  // one 32-k slab: 8 ds_reads + 32 MFMAs, rolls w2 prefetch
  auto slab_step = [&](int cur, int slab) {
    s8v cb0 = nb0, cb1 = nb1, cb2 = nb2, cb3 = nb3;
    if (slab < 15) {
      const ushort* wb = wbase + (slab + 1) * 16384;
      nb0 = *(const s8v*)wb;
      nb1 = *(const s8v*)(wb + 512);
      nb2 = *(const s8v*)(wb + 1024);
      nb3 = *(const s8v*)(wb + 1536);
    }
    int ks = slab & 3;
#pragma unroll
    for (int mf = 0; mf < 8; ++mf) {
      int p = mf * 16 + l15;
      int off = (p * 256 + ks * 64 + lg * 16) ^ ((p & 7) << 4);
      s8v a = *(const s8v*)((const char*)h1s[cur] + off);
      acc[mf][0] = __builtin_amdgcn_mfma_f32_16x16x32_bf16(a, cb0, acc[mf][0], 0, 0, 0);
      acc[mf][1] = __builtin_amdgcn_mfma_f32_16x16x32_bf16(a, cb1, acc[mf][1], 0, 0, 0);
      acc[mf][2] = __builtin_amdgcn_mfma_f32_16x16x32_bf16(a, cb2, acc[mf][2], 0, 0, 0);
      acc[mf][3] = __builtin_amdgcn_mfma_f32_16x16x32_bf16(a, cb3, acc[mf][3], 0, 0, 0);
    }
  };

  for (int ch = 0; ch < 4; ++ch) {
    int cur = ch & 1;
    if (ch < 3) issue_half(ch + 1, 0);       // loads in flight under slabs 0-1
    slab_step(cur, ch * 4 + 0);
    slab_step(cur, ch * 4 + 1);
    if (ch < 3) {
      write_half(cur ^ 1, 0);                // counted vmcnt (w2 loads younger)
      issue_half(ch + 1, 1);                 // loads in flight under slabs 2-3
    }
    slab_step(cur, ch * 4 + 2);
    slab_step(cur, ch * 4 + 3);
    if (ch < 3) write_half(cur ^ 1, 1);
    __syncthreads();
  }

  // epilogue: h2 = relu(acc+b2); partial = h2 . w3 over this wave's 64 cols
  float bb[4], ww[4];
#pragma unroll
  for (int nf = 0; nf < 4; ++nf) {
    int col = wid * 64 + nf * 16 + l15;
    bb[nf] = b2[col];
    ww[nf] = w3[col];
  }
#pragma unroll
  for (int mf = 0; mf < 8; ++mf) {
    float ps[4];
#pragma unroll
    for (int e = 0; e < 4; ++e) {
      ps[e] = fmaxf(acc[mf][0][e] + bb[0], 0.f) * ww[0] +
              fmaxf(acc[mf][1][e] + bb[1], 0.f) * ww[1] +
              fmaxf(acc[mf][2][e] + bb[2], 0.f) * ww[2] +
              fmaxf(acc[mf][3][e] + bb[3], 0.f) * ww[3];
    }
#pragma unroll
    for (int m = 1; m < 16; m <<= 1) {
#pragma unroll
      for (int e = 0; e < 4; ++e) ps[e] += __shfl_xor(ps[e], m);
    }
    if (l15 == 0) {
#pragma unroll
      for (int e = 0; e < 4; ++e)
        part[wid][mf * 16 + lg * 4 + e] = ps[e];
    }
  }
  __syncthreads();
  if (tid < 128) {
    float tot = b3[0];
#pragma unroll
    for (int w = 0; w < 8; ++w) tot += part[w][tid];
    float sg = 1.f / (1.f + expf(-tot));
    int i = bi * 8 + (tid >> 4);
    int j = bj * 16 + (tid & 15);
    if (i < j) {
      edges[i * NN + j] = sg;
      edges[j * NN + i] = sg;
    } else if (i == j) {
      edges[i * NN + i] = 0.f;
    }
  }
}

extern "C" void kernel_launch(void* const* d_in, const int* in_sizes, int n_in,
                              void* d_out, int out_size, void* d_ws, size_t ws_size,
                              hipStream_t stream) {
  const float* node = (const float*)d_in[0];
  const float* adj  = (const float*)d_in[1];
  const float* g1wl = (const float*)d_in[2];
  const float* g1bl = (const float*)d_in[3];
  const float* g1ws = (const float*)d_in[4];
  const float* g1bs = (const float*)d_in[5];
  const float* g2wl = (const float*)d_in[6];
  const float* g2bl = (const float*)d_in[7];
  const float* g2ws = (const float*)d_in[8];
  const float* g2bs = (const float*)d_in[9];
  const float* g3wl = (const float*)d_in[10];
  const float* g3bl = (const float*)d_in[11];
  const float* g3ws = (const float*)d_in[12];
  const float* g3bs = (const float*)d_in[13];
  const float* w1 = (const float*)d_in[14];
  const float* b1 = (const float*)d_in[15];
  const float* w2 = (const float*)d_in[16];
  const float* b2 = (const float*)d_in[17];
  const float* w3 = (const float*)d_in[18];
  const float* b3 = (const float*)d_in[19];

  float* out = (float*)d_out;
  float* emb = out;                 // [512][256]
  float* edges = out + NN * FF;     // [512][512]

  char* wsb = (char*)d_ws;
  float* adjn = (float*)wsb;                     // 1 MB
  float* Tb   = (float*)(wsb + (1u << 20));      // 1 MB
  float* Sb   = (float*)(wsb + (2u << 20));      // 1 MB
  float* xa   = (float*)(wsb + (3u << 20));      // 1 MB
  float* xb   = (float*)(wsb + (4u << 20));      // 1 MB
  ushort* w2t2 = (ushort*)(wsb + (5u << 20));    // 512 KB
  float* Amat = Tb;  // reused after GCN
  float* Bmat = Sb;

  rownorm_kernel<<<NN, 256, 0, stream>>>(adj, adjn);
  w2_pack<<<dim3(8, 16), 256, 0, stream>>>(w2, w2t2);

  // ---- GCN layer 1: T=x@wl+bl, S=x@ws+bs ; xa=relu(adjn@T+S)
  gemm_ts<false><<<dim3(8, 32, 2), 256, 0, stream>>>(
      NN, HH, FF, node, FF, g1wl, g1ws, HH, g1bl, g1bs,
      nullptr, nullptr, 0, Tb, Sb, HH);
  gemm_ts<true><<<dim3(8, 32, 1), 256, 0, stream>>>(
      NN, HH, NN, adjn, NN, Tb, Tb, HH, nullptr, nullptr,
      Sb, Sb, HH, xa, xa, HH);
  // ---- GCN layer 2
  gemm_ts<false><<<dim3(8, 32, 2), 256, 0, stream>>>(
      NN, HH, HH, xa, HH, g2wl, g2ws, HH, g2bl, g2bs,
      nullptr, nullptr, 0, Tb, Sb, HH);
  gemm_ts<true><<<dim3(8, 32, 1), 256, 0, stream>>>(
      NN, HH, NN, adjn, NN, Tb, Tb, HH, nullptr, nullptr,
      Sb, Sb, HH, xb, xb, HH);
  // ---- GCN layer 3 (no relu) -> emb (d_out)
  gemm_ts<false><<<dim3(4, 32, 2), 256, 0, stream>>>(
      NN, FF, HH, xb, HH, g3wl, g3ws, FF, g3bl, g3bs,
      nullptr, nullptr, 0, Tb, Sb, FF);
  gemm_ts<false><<<dim3(4, 32, 1), 256, 0, stream>>>(
      NN, FF, NN, adjn, NN, Tb, Tb, FF, nullptr, nullptr,
      Sb, Sb, FF, emb, emb, FF);

  // ---- edge MLP layer-1 factorization: Amat = emb@w1_top+b1, Bmat = emb@w1_bot
  gemm_ts<false><<<dim3(8, 32, 2), 256, 0, stream>>>(
      NN, HH, FF, emb, FF, w1, w1 + FF * HH, HH, b1, nullptr,
      nullptr, nullptr, 0, Amat, Bmat, HH);

  // ---- fused edge MLP: exact triangular grid (32^2 + 32 = 1056 tiles)
  edge_mlp<<<1056, 512, 0, stream>>>(Amat, Bmat, w2t2, b2, w3, b3, edges);
}